// Round 8
// baseline (101.050 us; speedup 1.0000x reference)
//
#include <hip/hip_runtime.h>
#include <math.h>

// Poincare-ball KG scoring (MuRP-style) for MI355X, v8 -- DIAGNOSTIC ROUND.
// v5 (best, 48us) kept as the real kernel. Two full-size ablation dispatches
// added (results to d_ws scratch, NOT d_out):
//   gather_only_kernel  = v5 gather path + LDS readback, no math
//   compute_only_kernel = v5 math with gathers redirected to 32 hot rows
// rocprof per-dispatch dur splits the invariant ~50us between the two.

#define EPSF 1e-5f
#define MAXN (1.0f - 1e-5f)

__device__ __forceinline__ float dot4(const float4 a, const float4 b) {
    return a.x*b.x + a.y*b.y + a.z*b.z + a.w*b.w;
}

__device__ __forceinline__ unsigned bfpack(unsigned lo, unsigned hi) {
    unsigned bl = (lo + 0x7FFFu + ((lo >> 16) & 1u)) >> 16;
    unsigned bh = (hi + 0x7FFFu + ((hi >> 16) & 1u)) & 0xFFFF0000u;
    return (bl & 0xFFFFu) | bh;
}

__global__ __launch_bounds__(256) void cvt_bf16_kernel(
    const uint4* __restrict__ src, uint4* __restrict__ dst, int ngroups)
{
    int i = blockIdx.x * 256 + threadIdx.x;
    if (i >= ngroups) return;
    uint4 a = src[2*i], b = src[2*i+1];
    uint4 o;
    o.x = bfpack(a.x, a.y); o.y = bfpack(a.z, a.w);
    o.z = bfpack(b.x, b.y); o.w = bfpack(b.z, b.w);
    dst[i] = o;
}

__device__ __forceinline__ float bflo(unsigned u){ return __uint_as_float(u<<16); }
__device__ __forceinline__ float bfhi(unsigned u){ return __uint_as_float(u&0xFFFF0000u); }

__device__ __forceinline__ void gload_lds16(const void* g, void* l) {
    typedef const __attribute__((address_space(1))) unsigned int GU;
    typedef __attribute__((address_space(3))) unsigned int LU;
    __builtin_amdgcn_global_load_lds((GU*)g, (LU*)l, 16, 0, 0);
}

// ============ ABLATION A: gather path only (v5 structure) ============
__global__ __launch_bounds__(256, 4) void gather_only_kernel(
    const char* __restrict__ Ehb, const int* __restrict__ head_idx,
    const int* __restrict__ tail_idx, float* __restrict__ wsout, int total)
{
    __shared__ uint4 lds[4][512];
    const int lane = threadIdx.x & 63;
    const int wave = threadIdx.x >> 6;
    const int sub  = lane & 3;
    const int e    = blockIdx.x * 64 + wave * 16 + (lane >> 2);
    const int ec   = (e < total) ? e : (total - 1);

    const int hi = head_idx[ec];
    const int ti = tail_idx[ec];
    uint4* __restrict__ ldsw = lds[wave];
    const char* hg = Ehb + ((size_t)(unsigned)hi << 8) + (sub << 4);
    const char* tg = Ehb + ((size_t)(unsigned)ti << 8) + (sub << 4);
#pragma unroll
    for (int k = 0; k < 4; ++k)
        gload_lds16(hg + k * 64, (void*)(ldsw + k * 64));
#pragma unroll
    for (int k = 0; k < 4; ++k)
        gload_lds16(tg + k * 64, (void*)(ldsw + 256 + k * 64));

    asm volatile("s_waitcnt vmcnt(0)" ::: "memory");
    __builtin_amdgcn_sched_barrier(0);

    // consume the same LDS volume as the real kernel (8x ds_read_b128/lane)
    unsigned s = 0;
#pragma unroll
    for (int k = 0; k < 4; ++k) {
        uint4 a = ldsw[k * 64 + lane];
        uint4 b = ldsw[256 + k * 64 + lane];
        s ^= a.x ^ a.y ^ a.z ^ a.w ^ b.x ^ b.y ^ b.z ^ b.w;
    }
    s ^= (unsigned)__shfl_xor((int)s, 1);
    s ^= (unsigned)__shfl_xor((int)s, 2);
    if (lane == 0) wsout[blockIdx.x * 4 + wave] = __uint_as_float(s);
}

// ============ ABLATION B: compute path only (gathers -> 32 hot rows) ======
__global__ __launch_bounds__(256, 4) void compute_only_kernel(
    const char* __restrict__ Ehb, const float* __restrict__ rvh,
    const float* __restrict__ W, const float* __restrict__ bias0,
    const float* __restrict__ bias1, const int* __restrict__ head_idx,
    const int* __restrict__ rel_idx, const int* __restrict__ tail_idx,
    float* __restrict__ wsout, int total)
{
    __shared__ uint4 lds[4][512];
    const int lane  = threadIdx.x & 63;
    const int wave  = threadIdx.x >> 6;
    const int sub   = lane & 3;
    const int e     = blockIdx.x * 64 + wave * 16 + (lane >> 2);
    const int ec    = (e < total) ? e : (total - 1);

    const int hi = head_idx[ec];
    const int ri = rel_idx[ec];
    const int ti = tail_idx[ec];

    uint4* __restrict__ ldsw = lds[wave];
    // FIXED hot rows (32 rows x 256B = 8KB, L1/L2-resident)
    const int hif = (lane >> 2);
    const int tif = 16 + (lane >> 2);
    const char* hg = Ehb + ((size_t)hif << 8) + (sub << 4);
    const char* tg = Ehb + ((size_t)tif << 8) + (sub << 4);
#pragma unroll
    for (int k = 0; k < 4; ++k)
        gload_lds16(hg + k * 64, (void*)(ldsw + k * 64));
#pragma unroll
    for (int k = 0; k < 4; ++k)
        gload_lds16(tg + k * 64, (void*)(ldsw + 256 + k * 64));

    const float4* __restrict__ rrow =
        reinterpret_cast<const float4*>(rvh) + (size_t)ri * 32 + sub * 2;
    const float4* __restrict__ wrow =
        reinterpret_cast<const float4*>(W)   + (size_t)ri * 32 + sub * 2;

    asm volatile("s_waitcnt vmcnt(0)" ::: "memory");
    __builtin_amdgcn_sched_barrier(0);

    float H2 = 0.f, T2 = 0.f, R2 = 0.f, TR = 0.f;
    float HW2 = 0.f, HWT = 0.f, HWR = 0.f;
#pragma unroll
    for (int k = 0; k < 4; ++k) {
        uint4 hq = ldsw[k * 64 + lane];
        uint4 tq = ldsw[256 + k * 64 + lane];
        float4 r0 = rrow[k * 8], r1 = rrow[k * 8 + 1];
        float4 w0 = wrow[k * 8], w1 = wrow[k * 8 + 1];

        float4 ha = make_float4(bflo(hq.x), bfhi(hq.x), bflo(hq.y), bfhi(hq.y));
        float4 hb = make_float4(bflo(hq.z), bfhi(hq.z), bflo(hq.w), bfhi(hq.w));
        float4 ta = make_float4(bflo(tq.x), bfhi(tq.x), bflo(tq.y), bfhi(tq.y));
        float4 tb = make_float4(bflo(tq.z), bfhi(tq.z), bflo(tq.w), bfhi(tq.w));

        float4 hwa, hwb;
        hwa.x = ha.x*w0.x; hwa.y = ha.y*w0.y; hwa.z = ha.z*w0.z; hwa.w = ha.w*w0.w;
        hwb.x = hb.x*w1.x; hwb.y = hb.y*w1.y; hwb.z = hb.z*w1.z; hwb.w = hb.w*w1.w;

        H2  += dot4(ha,ha)   + dot4(hb,hb);
        T2  += dot4(ta,ta)   + dot4(tb,tb);
        R2  += dot4(r0,r0)   + dot4(r1,r1);
        TR  += dot4(ta,r0)   + dot4(tb,r1);
        HW2 += dot4(hwa,hwa) + dot4(hwb,hwb);
        HWT += dot4(hwa,ta)  + dot4(hwb,tb);
        HWR += dot4(hwa,r0)  + dot4(hwb,r1);
    }
#pragma unroll
    for (int m = 1; m <= 2; m <<= 1) {
        H2  += __shfl_xor(H2,  m);
        T2  += __shfl_xor(T2,  m);
        R2  += __shfl_xor(R2,  m);
        TR  += __shfl_xor(TR,  m);
        HW2 += __shfl_xor(HW2, m);
        HWT += __shfl_xor(HWT, m);
        HWR += __shfl_xor(HWR, m);
    }

    float nh = sqrtf(H2 + 1e-15f);
    float sh = (nh > MAXN) ? (MAXN / nh) : 1.0f;
    float h2 = H2 * sh * sh;
    float nt = sqrtf(T2 + 1e-15f);
    float st = (nt > MAXN) ? (MAXN / nt) : 1.0f;
    float t2 = T2 * st * st;
    float nr = sqrtf(R2 + 1e-15f);
    float sr = (nr > MAXN) ? (MAXN / nr) : 1.0f;
    float r2 = R2 * sr * sr;
    float xy = TR * st * sr;

    float nl = sqrtf(h2 + 1e-15f);
    nl = fminf(fmaxf(nl, EPSF), MAXN);
    float lf = 0.5f * logf((1.0f + nl) / (1.0f - nl)) / nl;
    float a0 = lf * sh;
    float v2 = a0 * a0 * HW2;
    float nv = fmaxf(sqrtf(v2 + 1e-15f), EPSF);
    float ef = tanhf(nv) / nv;
    float b0 = ef * a0;
    float hd2 = b0 * b0 * HW2;
    float nhd = sqrtf(hd2 + 1e-15f);
    float shd = (nhd > MAXN) ? (MAXN / nhd) : 1.0f;
    float b = b0 * shd;
    hd2 = b * b * HW2;

    float ct  = 1.0f + 2.0f * xy + r2;
    float cr  = 1.0f - t2;
    float den = fmaxf(1.0f + 2.0f * xy + t2 * r2, EPSF);
    float id  = 1.0f / den;
    float p = id * ct * st;
    float q = id * cr * sr;
    float tl2 = p*p*T2 + 2.0f*p*q*TR + q*q*R2;
    float ntl = sqrtf(tl2 + 1e-15f);
    float stl = (ntl > MAXN) ? (MAXN / ntl) : 1.0f;
    p *= stl; q *= stl;
    tl2 = tl2 * stl * stl;

    float hdtl = b * (p * HWT + q * HWR);
    float d2   = hd2 + tl2 - 2.0f * hdtl;
    float dn   = fmaxf((1.0f - hd2) * (1.0f - tl2), EPSF);
    float arg  = fmaxf(1.0f + 2.0f * d2 / dn, 1.0f + 1e-7f);
    float dist = acoshf(arg);

    if (sub == 0 && e < total)
        wsout[e] = bias0[hi] + bias1[ti] - dist;
}

// ============ REAL KERNEL: v5 verbatim (best: 48us) ============
__global__ __launch_bounds__(256, 4) void poincare_score_lds_kernel(
    const char* __restrict__ Ehb, const float* __restrict__ rvh,
    const float* __restrict__ W, const float* __restrict__ bias0,
    const float* __restrict__ bias1, const int* __restrict__ head_idx,
    const int* __restrict__ rel_idx, const int* __restrict__ tail_idx,
    float* __restrict__ out, int total)
{
    __shared__ uint4 lds[4][512];

    const int lane  = threadIdx.x & 63;
    const int wave  = threadIdx.x >> 6;
    const int sub   = lane & 3;
    const int e     = blockIdx.x * 64 + wave * 16 + (lane >> 2);
    const int ec    = (e < total) ? e : (total - 1);

    const int hi = head_idx[ec];
    const int ri = rel_idx[ec];
    const int ti = tail_idx[ec];

    uint4* __restrict__ ldsw = lds[wave];

    const char* hg = Ehb + ((size_t)(unsigned)hi << 8) + (sub << 4);
    const char* tg = Ehb + ((size_t)(unsigned)ti << 8) + (sub << 4);

#pragma unroll
    for (int k = 0; k < 4; ++k)
        gload_lds16(hg + k * 64, (void*)(ldsw + k * 64));
#pragma unroll
    for (int k = 0; k < 4; ++k)
        gload_lds16(tg + k * 64, (void*)(ldsw + 256 + k * 64));

    const float4* __restrict__ rrow =
        reinterpret_cast<const float4*>(rvh) + (size_t)ri * 32 + sub * 2;
    const float4* __restrict__ wrow =
        reinterpret_cast<const float4*>(W)   + (size_t)ri * 32 + sub * 2;

    asm volatile("s_waitcnt vmcnt(0)" ::: "memory");
    __builtin_amdgcn_sched_barrier(0);

    float H2 = 0.f, T2 = 0.f, R2 = 0.f, TR = 0.f;
    float HW2 = 0.f, HWT = 0.f, HWR = 0.f;

#pragma unroll
    for (int k = 0; k < 4; ++k) {
        uint4 hq = ldsw[k * 64 + lane];
        uint4 tq = ldsw[256 + k * 64 + lane];
        float4 r0 = rrow[k * 8], r1 = rrow[k * 8 + 1];
        float4 w0 = wrow[k * 8], w1 = wrow[k * 8 + 1];

        float4 ha = make_float4(bflo(hq.x), bfhi(hq.x), bflo(hq.y), bfhi(hq.y));
        float4 hb = make_float4(bflo(hq.z), bfhi(hq.z), bflo(hq.w), bfhi(hq.w));
        float4 ta = make_float4(bflo(tq.x), bfhi(tq.x), bflo(tq.y), bfhi(tq.y));
        float4 tb = make_float4(bflo(tq.z), bfhi(tq.z), bflo(tq.w), bfhi(tq.w));

        float4 hwa, hwb;
        hwa.x = ha.x*w0.x; hwa.y = ha.y*w0.y; hwa.z = ha.z*w0.z; hwa.w = ha.w*w0.w;
        hwb.x = hb.x*w1.x; hwb.y = hb.y*w1.y; hwb.z = hb.z*w1.z; hwb.w = hb.w*w1.w;

        H2  += dot4(ha,ha)   + dot4(hb,hb);
        T2  += dot4(ta,ta)   + dot4(tb,tb);
        R2  += dot4(r0,r0)   + dot4(r1,r1);
        TR  += dot4(ta,r0)   + dot4(tb,r1);
        HW2 += dot4(hwa,hwa) + dot4(hwb,hwb);
        HWT += dot4(hwa,ta)  + dot4(hwb,tb);
        HWR += dot4(hwa,r0)  + dot4(hwb,r1);
    }

#pragma unroll
    for (int m = 1; m <= 2; m <<= 1) {
        H2  += __shfl_xor(H2,  m);
        T2  += __shfl_xor(T2,  m);
        R2  += __shfl_xor(R2,  m);
        TR  += __shfl_xor(TR,  m);
        HW2 += __shfl_xor(HW2, m);
        HWT += __shfl_xor(HWT, m);
        HWR += __shfl_xor(HWR, m);
    }

    float nh = sqrtf(H2 + 1e-15f);
    float sh = (nh > MAXN) ? (MAXN / nh) : 1.0f;
    float h2 = H2 * sh * sh;

    float nt = sqrtf(T2 + 1e-15f);
    float st = (nt > MAXN) ? (MAXN / nt) : 1.0f;
    float t2 = T2 * st * st;

    float nr = sqrtf(R2 + 1e-15f);
    float sr = (nr > MAXN) ? (MAXN / nr) : 1.0f;
    float r2 = R2 * sr * sr;

    float xy = TR * st * sr;

    float nl = sqrtf(h2 + 1e-15f);
    nl = fminf(fmaxf(nl, EPSF), MAXN);
    float lf = 0.5f * logf((1.0f + nl) / (1.0f - nl)) / nl;
    float a0 = lf * sh;
    float v2 = a0 * a0 * HW2;

    float nv = fmaxf(sqrtf(v2 + 1e-15f), EPSF);
    float ef = tanhf(nv) / nv;
    float b0 = ef * a0;
    float hd2 = b0 * b0 * HW2;

    float nhd = sqrtf(hd2 + 1e-15f);
    float shd = (nhd > MAXN) ? (MAXN / nhd) : 1.0f;
    float b = b0 * shd;
    hd2 = b * b * HW2;

    float ct  = 1.0f + 2.0f * xy + r2;
    float cr  = 1.0f - t2;
    float den = fmaxf(1.0f + 2.0f * xy + t2 * r2, EPSF);
    float id  = 1.0f / den;
    float p = id * ct * st;
    float q = id * cr * sr;
    float tl2 = p*p*T2 + 2.0f*p*q*TR + q*q*R2;

    float ntl = sqrtf(tl2 + 1e-15f);
    float stl = (ntl > MAXN) ? (MAXN / ntl) : 1.0f;
    p *= stl; q *= stl;
    tl2 = tl2 * stl * stl;

    float hdtl = b * (p * HWT + q * HWR);
    float d2   = hd2 + tl2 - 2.0f * hdtl;
    float dn   = fmaxf((1.0f - hd2) * (1.0f - tl2), EPSF);
    float arg  = fmaxf(1.0f + 2.0f * d2 / dn, 1.0f + 1e-7f);
    float dist = acoshf(arg);

    if (sub == 0 && e < total) {
        out[e] = bias0[hi] + bias1[ti] - dist;
    }
}

// f32 fallback if ws too small
__global__ __launch_bounds__(256) void poincare_score_f32_kernel(
    const float* __restrict__ Eh, const float* __restrict__ rvh,
    const float* __restrict__ W, const float* __restrict__ bias0,
    const float* __restrict__ bias1, const int* __restrict__ head_idx,
    const int* __restrict__ rel_idx, const int* __restrict__ tail_idx,
    float* __restrict__ out, int total)
{
    const int tid   = threadIdx.x;
    const int lane4 = tid & 3;
    const int e     = blockIdx.x * 64 + (tid >> 2);
    if (e >= total) return;

    const int hi = head_idx[e];
    const int ri = rel_idx[e];
    const int ti = tail_idx[e];

    const float4* __restrict__ Eh4  = reinterpret_cast<const float4*>(Eh);
    const float4* __restrict__ rvh4 = reinterpret_cast<const float4*>(rvh);
    const float4* __restrict__ W4   = reinterpret_cast<const float4*>(W);

    const float4* __restrict__ hrow = Eh4  + (size_t)hi * 32 + lane4;
    const float4* __restrict__ trow = Eh4  + (size_t)ti * 32 + lane4;
    const float4* __restrict__ rrow = rvh4 + (size_t)ri * 32 + lane4;
    const float4* __restrict__ wrow = W4   + (size_t)ri * 32 + lane4;

    float H2 = 0.f, T2 = 0.f, R2 = 0.f, TR = 0.f;
    float HW2 = 0.f, HWT = 0.f, HWR = 0.f;
#pragma unroll
    for (int j = 0; j < 8; ++j) {
        float4 h = hrow[j * 4];
        float4 t = trow[j * 4];
        float4 r = rrow[j * 4];
        float4 w = wrow[j * 4];
        float4 hw;
        hw.x = h.x*w.x; hw.y = h.y*w.y; hw.z = h.z*w.z; hw.w = h.w*w.w;
        H2  += dot4(h, h);
        T2  += dot4(t, t);
        R2  += dot4(r, r);
        TR  += dot4(t, r);
        HW2 += dot4(hw, hw);
        HWT += dot4(hw, t);
        HWR += dot4(hw, r);
    }
#pragma unroll
    for (int m = 1; m <= 2; m <<= 1) {
        H2  += __shfl_xor(H2,  m);
        T2  += __shfl_xor(T2,  m);
        R2  += __shfl_xor(R2,  m);
        TR  += __shfl_xor(TR,  m);
        HW2 += __shfl_xor(HW2, m);
        HWT += __shfl_xor(HWT, m);
        HWR += __shfl_xor(HWR, m);
    }

    float nh = sqrtf(H2 + 1e-15f);
    float sh = (nh > MAXN) ? (MAXN / nh) : 1.0f;
    float h2 = H2 * sh * sh;
    float nt = sqrtf(T2 + 1e-15f);
    float st = (nt > MAXN) ? (MAXN / nt) : 1.0f;
    float t2 = T2 * st * st;
    float nr = sqrtf(R2 + 1e-15f);
    float sr = (nr > MAXN) ? (MAXN / nr) : 1.0f;
    float r2 = R2 * sr * sr;
    float xy = TR * st * sr;

    float nl = sqrtf(h2 + 1e-15f);
    nl = fminf(fmaxf(nl, EPSF), MAXN);
    float lf = 0.5f * logf((1.0f + nl) / (1.0f - nl)) / nl;
    float a0 = lf * sh;
    float v2 = a0 * a0 * HW2;
    float nv = fmaxf(sqrtf(v2 + 1e-15f), EPSF);
    float ef = tanhf(nv) / nv;
    float b0 = ef * a0;
    float hd2 = b0 * b0 * HW2;
    float nhd = sqrtf(hd2 + 1e-15f);
    float shd = (nhd > MAXN) ? (MAXN / nhd) : 1.0f;
    float b = b0 * shd;
    hd2 = b * b * HW2;

    float ct  = 1.0f + 2.0f * xy + r2;
    float cr  = 1.0f - t2;
    float den = fmaxf(1.0f + 2.0f * xy + t2 * r2, EPSF);
    float id  = 1.0f / den;
    float p = id * ct * st;
    float q = id * cr * sr;
    float tl2 = p * p * T2 + 2.0f * p * q * TR + q * q * R2;
    float ntl = sqrtf(tl2 + 1e-15f);
    float stl = (ntl > MAXN) ? (MAXN / ntl) : 1.0f;
    p *= stl; q *= stl;
    tl2 = tl2 * stl * stl;

    float hdtl = b * (p * HWT + q * HWR);
    float d2   = hd2 + tl2 - 2.0f * hdtl;
    float dn   = fmaxf((1.0f - hd2) * (1.0f - tl2), EPSF);
    float arg  = fmaxf(1.0f + 2.0f * d2 / dn, 1.0f + 1e-7f);
    float dist = acoshf(arg);

    if (lane4 == 0) {
        out[e] = bias0[hi] + bias1[ti] - dist;
    }
}

extern "C" void kernel_launch(void* const* d_in, const int* in_sizes, int n_in,
                              void* d_out, int out_size, void* d_ws, size_t ws_size,
                              hipStream_t stream) {
    const float* Eh       = (const float*)d_in[0];
    const float* rvh      = (const float*)d_in[1];
    const float* W        = (const float*)d_in[2];
    const float* bias0    = (const float*)d_in[3];
    const float* bias1    = (const float*)d_in[4];
    const int*   head_idx = (const int*)d_in[5];
    const int*   rel_idx  = (const int*)d_in[6];
    const int*   tail_idx = (const int*)d_in[7];
    float* out = (float*)d_out;

    const int total = in_sizes[5];             // B*K = 262144
    const int n_eh  = in_sizes[0];             // N_ENT * DIM
    const size_t needE = (size_t)n_eh * 2;     // bf16 Eh bytes
    const int blocks = (total + 63) / 64;

    // ablation scratch: checksums (16K floats) + per-element results
    const size_t abl_bytes = (size_t)blocks * 4 * 4 + (size_t)total * 4 + 256;

    if (ws_size >= needE && (n_eh & 7) == 0) {
        const int ngroups = n_eh / 8;
        const int cblocks = (ngroups + 255) / 256;
        cvt_bf16_kernel<<<cblocks, 256, 0, stream>>>(
            (const uint4*)Eh, (uint4*)d_ws, ngroups);

        if (ws_size >= needE + abl_bytes) {
            float* ws_g = (float*)((char*)d_ws + needE);
            float* ws_c = ws_g + (size_t)blocks * 4;
            gather_only_kernel<<<blocks, 256, 0, stream>>>(
                (const char*)d_ws, head_idx, tail_idx, ws_g, total);
            compute_only_kernel<<<blocks, 256, 0, stream>>>(
                (const char*)d_ws, rvh, W, bias0, bias1,
                head_idx, rel_idx, tail_idx, ws_c, total);
        }

        poincare_score_lds_kernel<<<blocks, 256, 0, stream>>>(
            (const char*)d_ws, rvh, W, bias0, bias1,
            head_idx, rel_idx, tail_idx, out, total);
    } else {
        poincare_score_f32_kernel<<<blocks, 256, 0, stream>>>(
            Eh, rvh, W, bias0, bias1, head_idx, rel_idx, tail_idx, out, total);
    }
}